// Round 6
// baseline (328.578 us; speedup 1.0000x reference)
//
#include <hip/hip_runtime.h>

// Broadcast a float from lane l via v_readlane (VALU pipe, uniform result).
__device__ __forceinline__ float rdlane(float v, int l) {
    return __int_as_float(__builtin_amdgcn_readlane(__float_as_int(v), l));
}

// max(x, dpp_shuffle(x)) — one butterfly step of a 64-lane max reduction.
template <int CTRL>
__device__ __forceinline__ float dpp_max_step(float x) {
    int t = __builtin_amdgcn_update_dpp(0, __float_as_int(x), CTRL, 0xF, 0xF, true);
    return fmaxf(x, __int_as_float(t));
}

// Full 64-lane max; result valid in lane 63 (invalid DPP lanes inject 0.0,
// harmless: keys are >=0 for alive rows; NaN/garbage dead lanes lose in
// IEEE fmaxf and fail the ==gmax ballot).
__device__ __forceinline__ float wave_max_to_lane63(float x) {
    x = dpp_max_step<0xB1>(x);   // xor 1
    x = dpp_max_step<0x4E>(x);   // xor 2
    x = dpp_max_step<0x141>(x);  // row_half_mirror (xor within 8)
    x = dpp_max_step<0x140>(x);  // row_mirror      (xor within 16)
    x = dpp_max_step<0x142>(x);  // row_bcast15     (16 -> 32)
    x = dpp_max_step<0x143>(x);  // row_bcast31     (32 -> 64)
    return x;
}

// Rounds 2-5 evidence: a 64-float live array per lane always ends up with an
// AGPR home (VGPR_Count stuck at 36-40; v_readlane can't source AGPRs ->
// v_accvgpr copy tax ~3.3x on the 2016 inner pairs; ~18k VALU/wave measured
// vs ~5.5k static; immune to launch_bounds, template unrolling, and asm "v"
// pins). Fix the ROOT CAUSE: shrink the frame. Two waves per matrix, column-
// parity striped: wave W owns columns {j : j&1==W}, lane i owns row i ->
// A[32]/lane (~60 reg frame, no spill pressure). Owner wave of column K does
// the pivot search and shares (m_i, p) via a double-buffered LDS slot; one
// barrier per k; both waves then update their ~16 columns with
// v_readlane + v_fma (pivot row is lane p inside EACH wave).
struct Shared {
    float m[2][2][64];   // [matrix][K&1][lane] multiplier vector
    int   p[2][2];       // [matrix][K&1] pivot lane
    float partial[2][2]; // [matrix][W] logdet halves
};

template <int K, int W>
struct LUStep {
    __device__ __forceinline__ static void run(float (&A)[32], float& flag,
            float& logdet, int lane, int mat, Shared* sh) {
        constexpr int OP = K & 1;   // owner parity of column K
        constexpr int kk = K >> 1;  // owner-local index of column K
        float mcoef;
        int p_s;
        if constexpr (W == OP) {
            // This wave owns column K: pivot search over alive rows.
            float key  = fabsf(A[kk]) + flag;   // -inf for dead rows
            float gmax = rdlane(wave_max_to_lane63(key), 63);
            unsigned long long ball = __ballot(key == gmax);
            p_s = (int)(__ffsll(ball) - 1);
            float pv  = rdlane(A[kk], p_s);
            float inv = __builtin_amdgcn_rcpf(pv);
            inv = inv * (2.0f - pv * inv);       // 1 Newton step (~0.5 ulp)
            logdet += __logf(fabsf(pv));
            mcoef = A[kk] * inv;                 // multiplier m_i, this lane
            sh->m[mat][OP][lane] = mcoef;
            if (lane == 0) sh->p[mat][OP] = p_s;
        }
        __syncthreads();
        if constexpr (W != OP) {
            int pv_ = sh->p[mat][OP];
            p_s    = __builtin_amdgcn_readfirstlane(pv_);
            mcoef  = sh->m[mat][OP][lane];
        }
        // Mark pivot row dead (both waves track identically).
        flag = (lane == p_s) ? -__builtin_huge_valf() : flag;
        // Update this wave's columns with global index 2*jj+W > K.
        constexpr int JLO = (K + 2 - W) >> 1;
#pragma unroll
        for (int jj = JLO; jj < 32; ++jj) {
            float s = rdlane(A[jj], p_s);           // pivot-row elem -> SGPR
            A[jj] = __builtin_fmaf(-mcoef, s, A[jj]); // VOP3 fma w/ neg mod
        }
        LUStep<K + 1, W>::run(A, flag, logdet, lane, mat, sh);
    }
};
template <int W>
struct LUStep<64, W> {
    __device__ __forceinline__ static void run(float (&)[32], float&, float&,
                                               int, int, Shared*) {}
};

template <int W>
__device__ __forceinline__ void run_half(const float* rp, float alpha, float off,
                                         int lane, int mat, Shared* sh,
                                         float* out, int b, int tid) {
    const float Lbox = 10.0f;
    const float PI_F = 3.14159265358979323846f;
    float x = rp[0], y = rp[1], z = rp[2];
    float sx, cx, sy, cy, sz, cz;
    __sincosf(x * (PI_F / Lbox), &sx, &cx);
    __sincosf(y * (PI_F / Lbox), &sy, &cy);
    __sincosf(z * (PI_F / Lbox), &sz, &cz);

    // Separable build: Phi[i][j] = ex[mx]*ey[my]*ez[mz], j = mx*16+my*4+mz.
    const float LPI = Lbox / PI_F;
    float ex[4], ey[4], ez[4];
#pragma unroll
    for (int m = 0; m < 4; ++m) {
        float sp, cp;
        __sincosf((PI_F * 0.25f) * ((float)m + off), &sp, &cp);
        float dx = LPI * (sx * cp - cx * sp);
        float dy = LPI * (sy * cp - cy * sp);
        float dz = LPI * (sz * cp - cz * sp);
        ex[m] = __expf(-alpha * dx * dx);
        ey[m] = __expf(-alpha * dy * dy);
        ez[m] = __expf(-alpha * dz * dz);
    }
    float exy[16];
#pragma unroll
    for (int q = 0; q < 16; ++q) exy[q] = ex[q >> 2] * ey[q & 3];
    float A[32];
#pragma unroll
    for (int jj = 0; jj < 32; ++jj) {
        constexpr int W_ = W;
        int j = 2 * jj + W_;                 // static after unroll
        A[jj] = exy[j >> 2] * ez[j & 3];
    }

    float flag = 0.0f, logdet = 0.0f;
    LUStep<0, W>::run(A, flag, logdet, lane, mat, sh);

    if (lane == 0) sh->partial[mat][W] = logdet;
    __syncthreads();
    if (tid == 0)
        out[b] = sh->partial[0][0] + sh->partial[0][1] +
                 sh->partial[1][0] + sh->partial[1][1];
}

// Block = 256 threads = 4 waves: (mat=0 waves 0,1)=up, (mat=1 waves 2,3)=dn.
__global__ __launch_bounds__(256, 4) void slater_logdet_kernel(
        const float* __restrict__ rs, const float* __restrict__ log_alpha_p,
        float* __restrict__ out) {
    const int b    = blockIdx.x;
    const int tid  = threadIdx.x;
    const int wv   = tid >> 6;
    const int mat  = wv >> 1;    // which spin / matrix
    const int wpar = wv & 1;     // column parity this wave owns
    const int lane = tid & 63;

    __shared__ Shared sh;

    const float Lbox = 10.0f;
    float alpha = __expf(log_alpha_p[0]);
    alpha = fminf(fmaxf(alpha, 0.5f / (Lbox * Lbox)), 200.0f / (Lbox * Lbox));

    const float* rp = rs + (size_t)b * 384 + (size_t)(mat * 64 + lane) * 3;
    const float off = mat ? 0.5f : 0.0f;

    if (wpar == 0)
        run_half<0>(rp, alpha, off, lane, mat, &sh, out, b, tid);
    else
        run_half<1>(rp, alpha, off, lane, mat, &sh, out, b, tid);
}

extern "C" void kernel_launch(void* const* d_in, const int* in_sizes, int n_in,
                              void* d_out, int out_size, void* d_ws, size_t ws_size,
                              hipStream_t stream) {
    const float* rs = (const float*)d_in[0];
    const float* la = (const float*)d_in[1];
    float* out      = (float*)d_out;
    slater_logdet_kernel<<<out_size, 256, 0, stream>>>(rs, la, out);
}

// Round 7
// 310.162 us; speedup vs baseline: 1.0594x; 1.0594x over previous
//
#include <hip/hip_runtime.h>

// Broadcast a float from lane l via v_readlane (VALU pipe, uniform result).
__device__ __forceinline__ float rdlane(float v, int l) {
    return __int_as_float(__builtin_amdgcn_readlane(__float_as_int(v), l));
}

// max(x, dpp_shuffle(x)) — one butterfly step of a 64-lane max reduction.
template <int CTRL>
__device__ __forceinline__ float dpp_max_step(float x) {
    int t = __builtin_amdgcn_update_dpp(0, __float_as_int(x), CTRL, 0xF, 0xF, true);
    return fmaxf(x, __int_as_float(t));
}

// Full 64-lane max; result valid in lane 63 (invalid DPP lanes inject 0.0,
// harmless here because keys are >= 0 for alive rows).
__device__ __forceinline__ float wave_max_to_lane63(float x) {
    x = dpp_max_step<0xB1>(x);   // xor 1
    x = dpp_max_step<0x4E>(x);   // xor 2
    x = dpp_max_step<0x141>(x);  // row_half_mirror (xor within 8)
    x = dpp_max_step<0x140>(x);  // row_mirror      (xor within 16)
    x = dpp_max_step<0x142>(x);  // row_bcast15     (16 -> 32)
    x = dpp_max_step<0x143>(x);  // row_bcast31     (32 -> 64)
    return x;
}

// Rounds 2-6 evidence: runtime tracks the machine-wide count of
// readlane->fmac DEPENDENT pairs (~13 cyc/pair), independent of frame size,
// occupancy, wave count, or asm register pins. Working theory: the SGPR
// write->VALU read hazard after v_readlane stalls SIMD issue and co-resident
// waves don't hide it. Fix: explicit software scheduling — one asm block per
// 8 columns: 8 back-to-back readlanes into 8 SGPRs, THEN 8 fmacs. Each
// readlane's consumer is >=7 instructions (>=14 cyc) downstream -> no stall.
template <int J0, int CNT>
struct Upd {
    __device__ __forceinline__ static void run(float (&A)[64], float negm, int p) {
        if constexpr (CNT >= 8) {
            float s0, s1, s2, s3, s4, s5, s6, s7;
            asm("v_readlane_b32 %0, %8, %17\n\t"
                "v_readlane_b32 %1, %9, %17\n\t"
                "v_readlane_b32 %2, %10, %17\n\t"
                "v_readlane_b32 %3, %11, %17\n\t"
                "v_readlane_b32 %4, %12, %17\n\t"
                "v_readlane_b32 %5, %13, %17\n\t"
                "v_readlane_b32 %6, %14, %17\n\t"
                "v_readlane_b32 %7, %15, %17\n\t"
                "v_fmac_f32 %8, %0, %16\n\t"
                "v_fmac_f32 %9, %1, %16\n\t"
                "v_fmac_f32 %10, %2, %16\n\t"
                "v_fmac_f32 %11, %3, %16\n\t"
                "v_fmac_f32 %12, %4, %16\n\t"
                "v_fmac_f32 %13, %5, %16\n\t"
                "v_fmac_f32 %14, %6, %16\n\t"
                "v_fmac_f32 %15, %7, %16"
                : "=&s"(s0), "=&s"(s1), "=&s"(s2), "=&s"(s3),
                  "=&s"(s4), "=&s"(s5), "=&s"(s6), "=&s"(s7),
                  "+v"(A[J0+0]), "+v"(A[J0+1]), "+v"(A[J0+2]), "+v"(A[J0+3]),
                  "+v"(A[J0+4]), "+v"(A[J0+5]), "+v"(A[J0+6]), "+v"(A[J0+7])
                : "v"(negm), "s"(p));
            Upd<J0 + 8, CNT - 8>::run(A, negm, p);
        } else if constexpr (CNT >= 4) {
            float s0, s1, s2, s3;
            asm("v_readlane_b32 %0, %4, %9\n\t"
                "v_readlane_b32 %1, %5, %9\n\t"
                "v_readlane_b32 %2, %6, %9\n\t"
                "v_readlane_b32 %3, %7, %9\n\t"
                "v_fmac_f32 %4, %0, %8\n\t"
                "v_fmac_f32 %5, %1, %8\n\t"
                "v_fmac_f32 %6, %2, %8\n\t"
                "v_fmac_f32 %7, %3, %8"
                : "=&s"(s0), "=&s"(s1), "=&s"(s2), "=&s"(s3),
                  "+v"(A[J0+0]), "+v"(A[J0+1]), "+v"(A[J0+2]), "+v"(A[J0+3])
                : "v"(negm), "s"(p));
            Upd<J0 + 4, CNT - 4>::run(A, negm, p);
        } else if constexpr (CNT >= 2) {
            float s0, s1;
            asm("v_readlane_b32 %0, %2, %5\n\t"
                "v_readlane_b32 %1, %3, %5\n\t"
                "v_fmac_f32 %2, %0, %4\n\t"
                "v_fmac_f32 %3, %1, %4"
                : "=&s"(s0), "=&s"(s1), "+v"(A[J0+0]), "+v"(A[J0+1])
                : "v"(negm), "s"(p));
            Upd<J0 + 2, CNT - 2>::run(A, negm, p);
        } else if constexpr (CNT == 1) {
            float s0;
            asm("v_readlane_b32 %0, %1, %3\n\t"
                "v_fmac_f32 %1, %0, %2"
                : "=&s"(s0), "+v"(A[J0])
                : "v"(negm), "s"(p));
        }
    }
};

// One LU elimination step, K compile-time (template recursion = full unroll).
template <int K>
struct LUStep {
    __device__ __forceinline__ static void run(float (&A)[64], float& flag,
                                               float& logdet, int lane) {
        // key = |A[K]| for alive rows, -inf for dead (pivot-consumed) rows
        float key  = fabsf(A[K]) + flag;
        float gmax = rdlane(wave_max_to_lane63(key), 63);
        unsigned long long ball = __ballot(key == gmax);
        int p = (int)(__ffsll((unsigned long long)ball) - 1);

        float pv  = rdlane(A[K], p);
        float inv = __builtin_amdgcn_rcpf(pv);
        inv = inv * (2.0f - pv * inv);             // 1 Newton step (~0.5 ulp)
        logdet += __logf(fabsf(pv));

        flag = (lane == p) ? -__builtin_huge_valf() : flag;

        // One multiplier per lane; lane p self-annihilates (never read again),
        // dead lanes have A[K]~=0 so m~=0.
        float negm = -(A[K] * inv);
        Upd<K + 1, 63 - K>::run(A, negm, p);
        LUStep<K + 1>::run(A, flag, logdet, lane);
    }
};
template <>
struct LUStep<64> {
    __device__ __forceinline__ static void run(float (&)[64], float&, float&, int) {}
};

// One wave = one 64x64 matrix, lane i owns ROW i in registers A[0..63].
// Block = 128 threads: wave 0 -> spin-up matrix, wave 1 -> spin-dn matrix.
__global__ __launch_bounds__(128, 2) void slater_logdet_kernel(
        const float* __restrict__ rs, const float* __restrict__ log_alpha_p,
        float* __restrict__ out) {
    const int b    = blockIdx.x;
    const int tid  = threadIdx.x;
    const int wave = tid >> 6;   // 0 = up, 1 = dn
    const int lane = tid & 63;

    const float Lbox = 10.0f;
    const float PI_F = 3.14159265358979323846f;

    float alpha = __expf(log_alpha_p[0]);
    alpha = fminf(fmaxf(alpha, 0.5f / (Lbox * Lbox)), 200.0f / (Lbox * Lbox));

    // Electron position for this lane (row index = electron index).
    const float* rp = rs + (size_t)b * 384 + (size_t)(wave * 64 + lane) * 3;
    float x = rp[0], y = rp[1], z = rp[2];

    float sx, cx, sy, cy, sz, cz;
    __sincosf(x * (PI_F / Lbox), &sx, &cx);
    __sincosf(y * (PI_F / Lbox), &sy, &cy);
    __sincosf(z * (PI_F / Lbox), &sz, &cz);

    // Separable build: Phi[i][j] = ex[mx]*ey[my]*ez[mz], j = mx*16+my*4+mz.
    // Only 12 exps + ~80 muls per lane.
    const float off = wave ? 0.5f : 0.0f;
    const float LPI = Lbox / PI_F;
    float ex[4], ey[4], ez[4];
#pragma unroll
    for (int m = 0; m < 4; ++m) {
        float sp, cp;
        __sincosf((PI_F * 0.25f) * ((float)m + off), &sp, &cp);
        float dx = LPI * (sx * cp - cx * sp);
        float dy = LPI * (sy * cp - cy * sp);
        float dz = LPI * (sz * cp - cz * sp);
        ex[m] = __expf(-alpha * dx * dx);
        ey[m] = __expf(-alpha * dy * dy);
        ez[m] = __expf(-alpha * dz * dz);
    }
    float exy[16];
#pragma unroll
    for (int q = 0; q < 16; ++q) exy[q] = ex[q >> 2] * ey[q & 3];
    float A[64];
#pragma unroll
    for (int j = 0; j < 64; ++j) A[j] = exy[j >> 2] * ez[j & 3];

    // LU with partial pivoting, row-owner layout, no physical row swap:
    // pivot rows stay in their lane; flag = -inf marks them dead. det sign
    // is irrelevant (log|det|).
    float flag   = 0.0f;
    float logdet = 0.0f;
    LUStep<0>::run(A, flag, logdet, lane);

    // logdet is lane-uniform. Combine the two spins.
    __shared__ float partial[2];
    if (lane == 0) partial[wave] = logdet;
    __syncthreads();
    if (tid == 0) out[b] = partial[0] + partial[1];
}

extern "C" void kernel_launch(void* const* d_in, const int* in_sizes, int n_in,
                              void* d_out, int out_size, void* d_ws, size_t ws_size,
                              hipStream_t stream) {
    const float* rs = (const float*)d_in[0];
    const float* la = (const float*)d_in[1];
    float* out      = (float*)d_out;
    slater_logdet_kernel<<<out_size, 128, 0, stream>>>(rs, la, out);
}